// Round 3
// baseline (601.679 us; speedup 1.0000x reference)
//
#include <hip/hip_runtime.h>
#include <hip/hip_cooperative_groups.h>

namespace cg = cooperative_groups;

#define B_ 32
#define T_ 2048
#define D_ 512
#define GRID_ 1024   // 4 blocks/CU x 256 CUs; __launch_bounds__(256,4) keeps VGPR<=128

// One cooperative kernel, 4 phases separated by grid.sync():
//   P1: energy[b,t] = dot(key[b,t,:], q[b,:])        (all 1024 blocks)
//   P2: softmax over T per batch -> attn (d_out)     (blocks 0..31)
//   P3: partial[b,chunk,:] = sum_t attn*value        (all 1024 blocks)
//   P4: out[b,:] = sum over 32 chunk partials        (blocks 0..31)
__global__ __launch_bounds__(256, 4) void fused_attention_kernel(
    const float* __restrict__ q,
    const float* __restrict__ key,
    const float* __restrict__ value,
    float* __restrict__ out,       // [B, D]
    float* __restrict__ attn,      // [B, T]
    float* __restrict__ energy,    // ws [B, T]
    float* __restrict__ partial)   // ws [B, 32, D]
{
    cg::grid_group grid = cg::this_grid();

    __shared__ float  redm[4];
    __shared__ float  reds[4];
    __shared__ float  attn_s[64];
    __shared__ float4 red4[128];

    const int b_blk = blockIdx.x >> 5;     // batch for P1/P3 (32 blocks/batch)
    const int sub   = blockIdx.x & 31;     // chunk id within batch
    const int wave  = threadIdx.x >> 6;
    const int lane  = threadIdx.x & 63;

    // ---------------- Phase 1: energy ----------------
    {
        const float4 qv0 = ((const float4*)q)[b_blk * 128 + lane];
        const float4 qv1 = ((const float4*)q)[b_blk * 128 + 64 + lane];
        const int t0 = sub * 64 + wave * 16;               // 16 rows per wave
        const float4* kbase = (const float4*)key + ((size_t)b_blk * T_ + t0) * 128;
#pragma unroll 4
        for (int r = 0; r < 16; ++r) {
            const float4 k0 = kbase[r * 128 + lane];
            const float4 k1 = kbase[r * 128 + 64 + lane];
            float acc = k0.x * qv0.x + k0.y * qv0.y + k0.z * qv0.z + k0.w * qv0.w
                      + k1.x * qv1.x + k1.y * qv1.y + k1.z * qv1.z + k1.w * qv1.w;
#pragma unroll
            for (int off = 32; off >= 1; off >>= 1)
                acc += __shfl_down(acc, off);
            if (lane == 0)
                energy[b_blk * T_ + t0 + r] = acc;
        }
    }

    grid.sync();

    // ---------------- Phase 2: softmax (blocks 0..31) ----------------
    if (blockIdx.x < B_) {
        const int b = blockIdx.x;
        const float4* e4 = (const float4*)(energy + b * T_);
        float4 v0 = e4[threadIdx.x * 2 + 0];
        float4 v1 = e4[threadIdx.x * 2 + 1];

        float m = fmaxf(fmaxf(fmaxf(v0.x, v0.y), fmaxf(v0.z, v0.w)),
                        fmaxf(fmaxf(v1.x, v1.y), fmaxf(v1.z, v1.w)));
#pragma unroll
        for (int off = 32; off >= 1; off >>= 1)
            m = fmaxf(m, __shfl_xor(m, off));
        if (lane == 0) redm[wave] = m;
        __syncthreads();
        m = fmaxf(fmaxf(redm[0], redm[1]), fmaxf(redm[2], redm[3]));

        float4 x0, x1;
        x0.x = __expf(v0.x - m); x0.y = __expf(v0.y - m);
        x0.z = __expf(v0.z - m); x0.w = __expf(v0.w - m);
        x1.x = __expf(v1.x - m); x1.y = __expf(v1.y - m);
        x1.z = __expf(v1.z - m); x1.w = __expf(v1.w - m);
        float s = x0.x + x0.y + x0.z + x0.w + x1.x + x1.y + x1.z + x1.w;
#pragma unroll
        for (int off = 32; off >= 1; off >>= 1)
            s += __shfl_xor(s, off);
        if (lane == 0) reds[wave] = s;
        __syncthreads();
        s = reds[0] + reds[1] + reds[2] + reds[3];

        const float inv = 1.f / s;
        x0.x *= inv; x0.y *= inv; x0.z *= inv; x0.w *= inv;
        x1.x *= inv; x1.y *= inv; x1.z *= inv; x1.w *= inv;

        float4* a4 = (float4*)(attn + b * T_);
        a4[threadIdx.x * 2 + 0] = x0;
        a4[threadIdx.x * 2 + 1] = x1;
    }

    grid.sync();

    // ---------------- Phase 3: context partials ----------------
    {
        const int t0 = sub * 64;
        if (threadIdx.x < 64)
            attn_s[threadIdx.x] = attn[b_blk * T_ + t0 + threadIdx.x];
        __syncthreads();

        const int tg = threadIdx.x >> 7;   // row group 0..1
        const int d4 = threadIdx.x & 127;  // float4 slice of D

        const float4* v4 = (const float4*)value + ((size_t)b_blk * T_ + t0 + tg) * 128 + d4;
        float4 acc = {0.f, 0.f, 0.f, 0.f};
#pragma unroll 8
        for (int i = 0; i < 32; ++i) {     // t = t0 + 2*i + tg
            const float a = attn_s[2 * i + tg];
            const float4 vv = v4[i * 256];
            acc.x += a * vv.x; acc.y += a * vv.y;
            acc.z += a * vv.z; acc.w += a * vv.w;
        }

        if (tg == 1) red4[d4] = acc;
        __syncthreads();
        if (tg == 0) {
            const float4 o = red4[d4];
            acc.x += o.x; acc.y += o.y; acc.z += o.z; acc.w += o.w;
            ((float4*)partial)[((size_t)b_blk * 32 + sub) * 128 + d4] = acc;
        }
    }

    grid.sync();

    // ---------------- Phase 4: final reduce (blocks 0..31) ----------------
    if (blockIdx.x < B_ && threadIdx.x < 128) {
        const int b  = blockIdx.x;
        const int d4 = threadIdx.x;
        float4 s = {0.f, 0.f, 0.f, 0.f};
#pragma unroll
        for (int c = 0; c < 32; ++c) {
            const float4 p = ((const float4*)partial)[((size_t)b * 32 + c) * 128 + d4];
            s.x += p.x; s.y += p.y; s.z += p.z; s.w += p.w;
        }
        ((float4*)out)[b * 128 + d4] = s;
    }
}

extern "C" void kernel_launch(void* const* d_in, const int* in_sizes, int n_in,
                              void* d_out, int out_size, void* d_ws, size_t ws_size,
                              hipStream_t stream)
{
    const float* q     = (const float*)d_in[0];   // [B, D]
    const float* key   = (const float*)d_in[1];   // [B, T, D]
    const float* value = (const float*)d_in[2];   // [B, T, D]

    float* out  = (float*)d_out;                  // [B, D] first
    float* attn = out + B_ * D_;                  // [B, T] second

    float* energy  = (float*)d_ws;                // B*T floats     (256 KiB)
    float* partial = energy + B_ * T_;            // B*32*D floats  (2 MiB)

    void* args[] = {
        (void*)&q, (void*)&key, (void*)&value,
        (void*)&out, (void*)&attn, (void*)&energy, (void*)&partial
    };
    hipLaunchCooperativeKernel((void*)fused_attention_kernel,
                               dim3(GRID_), dim3(256), args, 0, stream);
}

// Round 4
// 284.532 us; speedup vs baseline: 2.1146x; 2.1146x over previous
//
#include <hip/hip_runtime.h>

#define B_ 32
#define T_ 2048
#define D_ 512
// 64 chunks of 32 rows per batch; 2048 blocks total for each heavy kernel.

// ---------------- Kernel A: energy + per-chunk softmax stats ----------------
// Block = (b, sub): 32 rows. 4 waves x 8 rows. Also zero-inits out[b,:] (sub==0).
// stats[b][sub] = (m_c = max e, s_c = sum exp(e - m_c)) over the 32 rows.
__global__ __launch_bounds__(256) void energy_stats_kernel(
    const float* __restrict__ q,
    const float* __restrict__ key,
    float* __restrict__ energy,     // ws [B, T]
    float* __restrict__ stats,      // ws [B, 64, 2]
    float* __restrict__ out)        // [B, D] zero-init here
{
    const int b    = blockIdx.x >> 6;
    const int sub  = blockIdx.x & 63;
    const int wave = threadIdx.x >> 6;
    const int lane = threadIdx.x & 63;

    if (sub == 0 && threadIdx.x < 128) {
        const float4 z = {0.f, 0.f, 0.f, 0.f};
        ((float4*)out)[b * 128 + threadIdx.x] = z;
    }

    __shared__ float es[32];

    const float4 qv0 = ((const float4*)q)[b * 128 + lane];
    const float4 qv1 = ((const float4*)q)[b * 128 + 64 + lane];

    const int t0 = sub * 32 + wave * 8;   // this wave's first row
    const float4* kbase = (const float4*)key + ((size_t)b * T_ + t0) * 128;

#pragma unroll
    for (int r = 0; r < 8; ++r) {
        const float4 k0 = kbase[r * 128 + lane];
        const float4 k1 = kbase[r * 128 + 64 + lane];
        float acc = k0.x * qv0.x + k0.y * qv0.y + k0.z * qv0.z + k0.w * qv0.w
                  + k1.x * qv1.x + k1.y * qv1.y + k1.z * qv1.z + k1.w * qv1.w;
#pragma unroll
        for (int off = 32; off >= 1; off >>= 1)
            acc += __shfl_down(acc, off);
        if (lane == 0) {
            es[wave * 8 + r] = acc;
            energy[b * T_ + t0 + r] = acc;
        }
    }
    __syncthreads();

    if (threadIdx.x < 32) {
        const float e = es[threadIdx.x];
        float m = e;
#pragma unroll
        for (int off = 16; off >= 1; off >>= 1)
            m = fmaxf(m, __shfl_xor(m, off));
        float s = __expf(e - m);
#pragma unroll
        for (int off = 16; off >= 1; off >>= 1)
            s += __shfl_xor(s, off);
        if (threadIdx.x == 0) {
            stats[((size_t)b * 64 + sub) * 2 + 0] = m;
            stats[((size_t)b * 64 + sub) * 2 + 1] = s;
        }
    }
}

// ---------------- Kernel B: combine stats -> attn -> context (atomicAdd) ----
// Block = (b, sub): 32 rows. Combines the batch's 64 chunk stats, writes
// attn[b, t0:t0+32], accumulates sum_t attn*value into out via atomicAdd.
__global__ __launch_bounds__(256) void context_kernel(
    const float* __restrict__ energy,
    const float* __restrict__ stats,
    const float* __restrict__ value,
    float* __restrict__ attn,       // [B, T] region of d_out
    float* __restrict__ out)        // [B, D]
{
    const int b   = blockIdx.x >> 6;
    const int sub = blockIdx.x & 63;
    const int t0  = sub * 32;
    const int tid = threadIdx.x;

    __shared__ float  MS[2];
    __shared__ float  attn_s[32];
    __shared__ float4 red4[128];

    // ---- combine 64 chunk stats (wave 0) ----
    if (tid < 64) {
        const float m_c = stats[((size_t)b * 64 + tid) * 2 + 0];
        const float s_c = stats[((size_t)b * 64 + tid) * 2 + 1];
        float M = m_c;
#pragma unroll
        for (int off = 32; off >= 1; off >>= 1)
            M = fmaxf(M, __shfl_xor(M, off));
        float S = s_c * __expf(m_c - M);
#pragma unroll
        for (int off = 32; off >= 1; off >>= 1)
            S += __shfl_xor(S, off);
        if (tid == 0) { MS[0] = M; MS[1] = S; }
    }
    __syncthreads();
    const float M    = MS[0];
    const float invS = 1.f / MS[1];

    // ---- attention for this chunk ----
    if (tid < 32) {
        const float e = energy[b * T_ + t0 + tid];
        const float a = __expf(e - M) * invS;
        attn_s[tid] = a;
        attn[b * T_ + t0 + tid] = a;
    }
    __syncthreads();

    // ---- context partial: 2 row-groups x 128 float4 d-slices ----
    const int tg = tid >> 7;            // 0..1
    const int d4 = tid & 127;           // float4 slice of D

    const float4* v4 = (const float4*)value + ((size_t)b * T_ + t0 + tg) * 128 + d4;
    float4 acc = {0.f, 0.f, 0.f, 0.f};
#pragma unroll
    for (int i = 0; i < 16; ++i) {      // t = t0 + 2*i + tg
        const float a = attn_s[2 * i + tg];
        const float4 vv = v4[i * 256];
        acc.x += a * vv.x; acc.y += a * vv.y;
        acc.z += a * vv.z; acc.w += a * vv.w;
    }

    if (tg == 1) red4[d4] = acc;
    __syncthreads();
    if (tg == 0) {
        const float4 o = red4[d4];
        acc.x += o.x; acc.y += o.y; acc.z += o.z; acc.w += o.w;
        float* dst = out + (size_t)b * D_ + d4 * 4;
        atomicAdd(dst + 0, acc.x);
        atomicAdd(dst + 1, acc.y);
        atomicAdd(dst + 2, acc.z);
        atomicAdd(dst + 3, acc.w);
    }
}

extern "C" void kernel_launch(void* const* d_in, const int* in_sizes, int n_in,
                              void* d_out, int out_size, void* d_ws, size_t ws_size,
                              hipStream_t stream)
{
    const float* q     = (const float*)d_in[0];   // [B, D]
    const float* key   = (const float*)d_in[1];   // [B, T, D]
    const float* value = (const float*)d_in[2];   // [B, T, D]

    float* out  = (float*)d_out;                  // [B, D] first
    float* attn = out + B_ * D_;                  // [B, T] second

    float* energy = (float*)d_ws;                 // B*T floats    (256 KiB)
    float* stats  = energy + B_ * T_;             // B*64*2 floats (16 KiB)

    energy_stats_kernel<<<B_ * 64, 256, 0, stream>>>(q, key, energy, stats, out);
    context_kernel<<<B_ * 64, 256, 0, stream>>>(energy, stats, value, attn, out);
}